// Round 5
// baseline (101.053 us; speedup 1.0000x reference)
//
#include <hip/hip_runtime.h>
#include <hip/hip_bf16.h>

typedef __attribute__((ext_vector_type(4))) float f32x4;
typedef __attribute__((ext_vector_type(8))) short short8;
typedef __attribute__((ext_vector_type(4))) unsigned short ushort4v;
typedef _Float16 f16x8 __attribute__((ext_vector_type(8)));

#define NB 8
#define NN 2048
#define NF 128
#define LOG2E 1.4426950408889634f
#define MASK_NEG_H -60000.0f

static __device__ __forceinline__ unsigned short f2bf(float f) {
    union { __hip_bfloat16 b; unsigned short u; } cv;
    cv.b = __float2bfloat16(f);
    return cv.u;
}

// ---------------------------------------------------------------------------
// Kernel A: h_prime = h @ W via bf16 MFMA -> vfrag (B-fragment order:
// vfrag[b][s][colt][lane][e], lane=(col&15)|(((j>>3)&3)<<4), e=j&7);
// siC/sjC = (h @ (W@a1,2)) * log2e in fp32 (exact GEMV, fused).
// ---------------------------------------------------------------------------
__global__ __launch_bounds__(256) void k_hprime(
    const float* __restrict__ h, const float* __restrict__ W,
    const float* __restrict__ a, unsigned short* __restrict__ vfrag,
    float* __restrict__ siC, float* __restrict__ sjC)
{
    __shared__ __align__(16) unsigned char WT[32768];  // W^T bf16, swizzled [col][f]
    __shared__ float wa1[NF], wa2[NF];

    const int t = threadIdx.x;
    const int lane = t & 63;
    const int w = t >> 6;                 // 4 waves
    const int b = blockIdx.x >> 5;
    const int i0 = (blockIdx.x & 31) << 6;

    {
        const int f = t >> 1;             // 0..127
        const int c0 = (t & 1) << 6;      // 0 or 64
        float s1 = 0.f, s2 = 0.f;
        const float* wrow = W + f * NF + c0;
        const float* a1p = a + c0;
        const float* a2p = a + NF + c0;
        #pragma unroll 8
        for (int c = 0; c < 64; ++c) {
            float wv = wrow[c];
            s1 += wv * a1p[c];
            s2 += wv * a2p[c];
            int col = c0 + c;
            int dst = col * 256 + ((2 * f) ^ ((col & 15) << 4));
            *reinterpret_cast<unsigned short*>(&WT[dst]) = f2bf(wv);
        }
        s1 += __shfl_xor(s1, 1);
        s2 += __shfl_xor(s2, 1);
        if ((t & 1) == 0) { wa1[f] = s1 * LOG2E; wa2[f] = s2 * LOG2E; }
    }
    __syncthreads();

    const int l15 = lane & 15;
    const int arow = i0 + w * 16 + l15;
    const int kofs = (lane >> 4) << 3;    // 0,8,16,24
    const float* hrow = h + (size_t)(b * NN + arow) * NF + kofs;
    const int swz = l15 << 4;

    f32x4 acc[8];
    #pragma unroll
    for (int nt = 0; nt < 8; ++nt) acc[nt] = (f32x4)(0.f);
    float s1 = 0.f, s2 = 0.f;

    #pragma unroll
    for (int k0 = 0; k0 < NF; k0 += 32) {
        f32x4 h0 = *reinterpret_cast<const f32x4*>(hrow + k0);
        f32x4 h1 = *reinterpret_cast<const f32x4*>(hrow + k0 + 4);
        f32x4 w1lo = *reinterpret_cast<const f32x4*>(&wa1[k0 + kofs]);
        f32x4 w1hi = *reinterpret_cast<const f32x4*>(&wa1[k0 + kofs + 4]);
        f32x4 w2lo = *reinterpret_cast<const f32x4*>(&wa2[k0 + kofs]);
        f32x4 w2hi = *reinterpret_cast<const f32x4*>(&wa2[k0 + kofs + 4]);
        short8 af;
        #pragma unroll
        for (int e = 0; e < 4; ++e) {
            s1 += h0[e] * w1lo[e] + h1[e] * w1hi[e];
            s2 += h0[e] * w2lo[e] + h1[e] * w2hi[e];
            af[e]     = (short)f2bf(h0[e]);
            af[4 + e] = (short)f2bf(h1[e]);
        }
        const int ib = (2 * (k0 + kofs)) ^ swz;
        #pragma unroll
        for (int nt = 0; nt < 8; ++nt) {
            short8 bf8 = *reinterpret_cast<short8*>(&WT[(nt * 16 + l15) * 256 + ib]);
            acc[nt] = __builtin_amdgcn_mfma_f32_16x16x32_bf16(af, bf8, acc[nt], 0, 0, 0);
        }
    }

    s1 += __shfl_xor(s1, 16); s1 += __shfl_xor(s1, 32);
    s2 += __shfl_xor(s2, 16); s2 += __shfl_xor(s2, 32);
    if (lane < 16) {
        siC[b * NN + arow] = s1;
        sjC[b * NN + arow] = s2;
    }

    // C layout: value at (j = J0 + e, col = nt*16 + l15) -> frag slot
    const int J0 = i0 + w * 16 + ((lane >> 4) << 2);
    const int s = J0 >> 5;
    const int jq = (J0 >> 3) & 3;
    const int eh = J0 & 7;                // 0 or 4
    #pragma unroll
    for (int nt = 0; nt < 8; ++nt) {
        ushort4v pk;
        #pragma unroll
        for (int e = 0; e < 4; ++e) pk[e] = f2bf(acc[nt][e]);
        *reinterpret_cast<ushort4v*>(
            vfrag + (((size_t)(b * 64 + s) * 8 + nt) * 64 + (l15 | (jq << 4))) * 8 + eh) = pk;
    }
}

// ---------------------------------------------------------------------------
// Kernel B: biasF in A-fragment order (fp16):
// biasF[iblk][s][lane][e] = bias[i = iblk*16 + (lane&15)][j = s*32 + (lane>>4)*8 + e]
// Coalesced reads of adj/dist, LDS transpose, coalesced 1KB frag writes.
// ---------------------------------------------------------------------------
__global__ __launch_bounds__(256) void k_bias(
    const int* __restrict__ adj, const float* __restrict__ dist,
    const float* __restrict__ scaler, _Float16* __restrict__ biasF)
{
    __shared__ __align__(16) _Float16 st[8][64][8];  // 8KB
    const int t = threadIdx.x;
    const int iblk = blockIdx.x >> 3;
    const int jch = blockIdx.x & 7;
    const int i_l = t >> 4;
    const int o2 = t & 15;
    const int i = iblk * 16 + i_l;
    const int jbase = jch * 256 + o2 * 16;
    const float sc = scaler[0];

    const int* ap = adj + (size_t)i * NN + jbase;
    const float* dp = dist + (size_t)i * NN + jbase;
    int av[16]; float dv[16];
    *reinterpret_cast<int4*>(&av[0])  = *reinterpret_cast<const int4*>(ap);
    *reinterpret_cast<int4*>(&av[4])  = *reinterpret_cast<const int4*>(ap + 4);
    *reinterpret_cast<int4*>(&av[8])  = *reinterpret_cast<const int4*>(ap + 8);
    *reinterpret_cast<int4*>(&av[12]) = *reinterpret_cast<const int4*>(ap + 12);
    *reinterpret_cast<float4*>(&dv[0])  = *reinterpret_cast<const float4*>(dp);
    *reinterpret_cast<float4*>(&dv[4])  = *reinterpret_cast<const float4*>(dp + 4);
    *reinterpret_cast<float4*>(&dv[8])  = *reinterpret_cast<const float4*>(dp + 8);
    *reinterpret_cast<float4*>(&dv[12]) = *reinterpret_cast<const float4*>(dp + 12);

    #pragma unroll
    for (int u = 0; u < 2; ++u) {
        const int sl = (o2 * 2 + u) >> 2;
        const int jq = (o2 * 2 + u) & 3;
        f16x8 pk;
        #pragma unroll
        for (int e = 0; e < 8; ++e) {
            const int idx = u * 8 + e;
            float v = (av[idx] > 0) ? (-__log2f(dv[idx] + 1e-6f) * sc) : MASK_NEG_H;
            pk[e] = (_Float16)v;
        }
        *reinterpret_cast<f16x8*>(&st[sl][i_l | (jq << 4)][0]) = pk;
    }
    __syncthreads();

    const int w = t >> 6, lane = t & 63;
    #pragma unroll
    for (int sub = 0; sub < 2; ++sub) {
        const int fs = w * 2 + sub;
        *reinterpret_cast<f16x8*>(
            biasF + ((size_t)(iblk * 64 + jch * 8 + fs) * 64 + lane) * 8) =
            *reinterpret_cast<f16x8*>(&st[fs][lane][0]);
    }
}

// ---------------------------------------------------------------------------
// Kernel C: barrier-free main loop, all loads frag-contiguous.
// 512 blocks = (b, rg of 64 rows, ch col-half) x 8 waves (js-strips of 256).
// Wave: 4 rowsets x 4 col-tiles x 8 K-steps; acc 64 VGPR; no LDS/barriers
// in main loop. Tail: half-acc LDS tree (32KB) + split epilogue.
// ---------------------------------------------------------------------------
__global__ __launch_bounds__(512, 4) void k_attn(
    const unsigned short* __restrict__ vfrag, const float* __restrict__ siC,
    const float* __restrict__ sjC, const _Float16* __restrict__ biasF,
    float* __restrict__ out)
{
    __shared__ __align__(16) float red[4][2048];   // 4 x 8KB
    __shared__ float lp[8][4][16];                 // 2KB

    const int t = threadIdx.x;
    const int lane = t & 63;
    const int w = t >> 6;          // js 0..7
    const int l15 = lane & 15;
    const int hi = lane >> 4;

    const int bid = blockIdx.x;
    const int b = bid & 7;         // XCD = batch
    const int rest = bid >> 3;
    const int rg = rest >> 1;      // 0..31 (64-row group)
    const int ch = rest & 1;       // col half

    float si_r[4];
    #pragma unroll
    for (int rs = 0; rs < 4; ++rs)
        si_r[rs] = siC[b * NN + rg * 64 + rs * 16 + l15];

    const float* sjp = sjC + b * NN + w * 256 + hi * 8;
    const _Float16* bp[4];
    #pragma unroll
    for (int rs = 0; rs < 4; ++rs)
        bp[rs] = biasF + ((size_t)((rg * 4 + rs) * 64 + w * 8) * 64 + lane) * 8;
    const unsigned short* vp[4];
    #pragma unroll
    for (int ct = 0; ct < 4; ++ct)
        vp[ct] = vfrag + (((size_t)(b * 64 + w * 8) * 8 + ch * 4 + ct) * 64 + lane) * 8;

    f32x4 acc[4][4];
    #pragma unroll
    for (int rs = 0; rs < 4; ++rs)
        #pragma unroll
        for (int ct = 0; ct < 4; ++ct) acc[rs][ct] = (f32x4)(0.f);
    float ls[4] = {0.f, 0.f, 0.f, 0.f};

    #pragma unroll 2
    for (int sl = 0; sl < 8; ++sl) {
        f32x4 sj0 = *reinterpret_cast<const f32x4*>(sjp + sl * 32);
        f32x4 sj1 = *reinterpret_cast<const f32x4*>(sjp + sl * 32 + 4);
        short8 pa[4];
        #pragma unroll
        for (int rs = 0; rs < 4; ++rs) {
            f16x8 bv = *reinterpret_cast<const f16x8*>(bp[rs] + sl * 512);
            #pragma unroll
            for (int e = 0; e < 8; ++e) {
                float x = si_r[rs] + ((e < 4) ? sj0[e] : sj1[e - 4]);
                float y = fmaxf(x, 0.2f * x) + (float)bv[e];
                float p = __builtin_amdgcn_exp2f(y);
                ls[rs] += p;
                pa[rs][e] = (short)f2bf(p);
            }
        }
        #pragma unroll
        for (int ct = 0; ct < 4; ++ct) {
            const short8 bfr = *reinterpret_cast<const short8*>(vp[ct] + sl * 4096);
            #pragma unroll
            for (int rs = 0; rs < 4; ++rs)
                acc[rs][ct] = __builtin_amdgcn_mfma_f32_16x16x32_bf16(pa[rs], bfr, acc[rs][ct], 0, 0, 0);
        }
    }

    #pragma unroll
    for (int rs = 0; rs < 4; ++rs) {
        ls[rs] += __shfl_xor(ls[rs], 16);
        ls[rs] += __shfl_xor(ls[rs], 32);
    }
    if (lane < 16) {
        #pragma unroll
        for (int rs = 0; rs < 4; ++rs) lp[w][rs][l15] = ls[rs];
    }

    #define WHALF(r, hh) { _Pragma("unroll") for (int rs = 0; rs < 4; ++rs)      \
        _Pragma("unroll") for (int c2 = 0; c2 < 2; ++c2)                         \
        *reinterpret_cast<f32x4*>(&red[r][((rs * 2 + c2) * 64 + lane) * 4]) =    \
            acc[rs][(hh) * 2 + c2]; }
    #define AHALF(r, hh) { _Pragma("unroll") for (int rs = 0; rs < 4; ++rs)      \
        _Pragma("unroll") for (int c2 = 0; c2 < 2; ++c2)                         \
        acc[rs][(hh) * 2 + c2] +=                                                \
            *reinterpret_cast<const f32x4*>(&red[r][((rs * 2 + c2) * 64 + lane) * 4]); }

    if (w & 1) WHALF(w >> 1, 0)
    __syncthreads();
    if (!(w & 1)) AHALF(w >> 1, 0)
    __syncthreads();
    if (w & 1) WHALF(w >> 1, 1)
    __syncthreads();
    if (!(w & 1)) AHALF(w >> 1, 1)
    __syncthreads();
    if (w == 2) WHALF(0, 0)
    if (w == 6) WHALF(1, 0)
    __syncthreads();
    if (w == 0) AHALF(0, 0)
    if (w == 4) AHALF(1, 0)
    __syncthreads();
    if (w == 2) WHALF(0, 1)
    if (w == 6) WHALF(1, 1)
    __syncthreads();
    if (w == 0) AHALF(0, 1)
    if (w == 4) AHALF(1, 1)
    __syncthreads();
    if (w == 4) WHALF(0, 0)
    if (w == 0) WHALF(1, 1)
    __syncthreads();
    if (w == 0) AHALF(0, 0)
    if (w == 4) AHALF(1, 1)

    if (w == 0 || w == 4) {
        const int ctb = (w == 0) ? 0 : 2;
        #pragma unroll
        for (int rs = 0; rs < 4; ++rs) {
            float linv[4];
            #pragma unroll
            for (int e = 0; e < 4; ++e) {
                float tot = 0.f;
                #pragma unroll
                for (int q = 0; q < 8; ++q) tot += lp[q][rs][(hi << 2) | e];
                linv[e] = 1.0f / tot;
            }
            #pragma unroll
            for (int c2 = 0; c2 < 2; ++c2) {
                const int col = ch * 64 + (ctb + c2) * 16 + l15;
                #pragma unroll
                for (int e = 0; e < 4; ++e) {
                    const int row = rg * 64 + rs * 16 + (hi << 2) + e;
                    float v = acc[rs][ctb + c2][e] * linv[e];
                    v = (v > 0.f) ? v : expm1f(v);
                    out[(size_t)(b * NN + row) * NF + col] = v;
                }
            }
        }
    }
    #undef WHALF
    #undef AHALF
}

extern "C" void kernel_launch(void* const* d_in, const int* in_sizes, int n_in,
                              void* d_out, int out_size, void* d_ws, size_t ws_size,
                              hipStream_t stream) {
    (void)in_sizes; (void)n_in; (void)out_size; (void)ws_size;
    const float* h      = (const float*)d_in[0];
    const int*   adj    = (const int*)d_in[1];
    const float* dist   = (const float*)d_in[2];
    const float* W      = (const float*)d_in[3];
    const float* a      = (const float*)d_in[4];
    const float* scaler = (const float*)d_in[5];
    float* out = (float*)d_out;

    char* ws = (char*)d_ws;
    unsigned short* vfrag = (unsigned short*)ws;                     // 4 MiB
    float* siC      = (float*)(ws + 4 * 1024 * 1024);                // 64 KiB
    float* sjC      = (float*)(ws + 4 * 1024 * 1024 + 65536);        // 64 KiB
    _Float16* biasF = (_Float16*)(ws + 4 * 1024 * 1024 + 2 * 65536); // 8 MiB

    k_hprime<<<dim3(NB * NN / 64), dim3(256), 0, stream>>>(h, W, a, vfrag, siC, sjC);
    k_bias<<<dim3(128 * 8), dim3(256), 0, stream>>>(adj, dist, scaler, biasF);
    k_attn<<<dim3(NB * NN / 32), dim3(512), 0, stream>>>(vfrag, siC, sjC, biasF, out);
}

// Round 6
// 100.367 us; speedup vs baseline: 1.0068x; 1.0068x over previous
//
#include <hip/hip_runtime.h>
#include <hip/hip_bf16.h>

typedef __attribute__((ext_vector_type(4))) float f32x4;
typedef __attribute__((ext_vector_type(8))) short short8;
typedef __attribute__((ext_vector_type(4))) unsigned short ushort4v;
typedef _Float16 f16x8 __attribute__((ext_vector_type(8)));

#define NB 8
#define NN 2048
#define NF 128
#define LOG2E 1.4426950408889634f
#define MASK_NEG_H -60000.0f

static __device__ __forceinline__ unsigned short f2bf(float f) {
    union { __hip_bfloat16 b; unsigned short u; } cv;
    cv.b = __float2bfloat16(f);
    return cv.u;
}

// ---------------------------------------------------------------------------
// Kernel A: h_prime = h @ W via bf16 MFMA -> vfrag (B-fragment order:
// vfrag[b][s][colt][lane][e]); siC/sjC = (h @ (W@a1,2)) * log2e fp32.
// ---------------------------------------------------------------------------
__global__ __launch_bounds__(256) void k_hprime(
    const float* __restrict__ h, const float* __restrict__ W,
    const float* __restrict__ a, unsigned short* __restrict__ vfrag,
    float* __restrict__ siC, float* __restrict__ sjC)
{
    __shared__ __align__(16) unsigned char WT[32768];  // W^T bf16, swizzled [col][f]
    __shared__ float wa1[NF], wa2[NF];

    const int t = threadIdx.x;
    const int lane = t & 63;
    const int w = t >> 6;                 // 4 waves
    const int b = blockIdx.x >> 5;
    const int i0 = (blockIdx.x & 31) << 6;

    {
        const int f = t >> 1;             // 0..127
        const int c0 = (t & 1) << 6;      // 0 or 64
        float s1 = 0.f, s2 = 0.f;
        const float* wrow = W + f * NF + c0;
        const float* a1p = a + c0;
        const float* a2p = a + NF + c0;
        #pragma unroll 8
        for (int c = 0; c < 64; ++c) {
            float wv = wrow[c];
            s1 += wv * a1p[c];
            s2 += wv * a2p[c];
            int col = c0 + c;
            int dst = col * 256 + ((2 * f) ^ ((col & 15) << 4));
            *reinterpret_cast<unsigned short*>(&WT[dst]) = f2bf(wv);
        }
        s1 += __shfl_xor(s1, 1);
        s2 += __shfl_xor(s2, 1);
        if ((t & 1) == 0) { wa1[f] = s1 * LOG2E; wa2[f] = s2 * LOG2E; }
    }
    __syncthreads();

    const int l15 = lane & 15;
    const int arow = i0 + w * 16 + l15;
    const int kofs = (lane >> 4) << 3;    // 0,8,16,24
    const float* hrow = h + (size_t)(b * NN + arow) * NF + kofs;
    const int swz = l15 << 4;

    f32x4 acc[8];
    #pragma unroll
    for (int nt = 0; nt < 8; ++nt) acc[nt] = (f32x4)(0.f);
    float s1 = 0.f, s2 = 0.f;

    #pragma unroll
    for (int k0 = 0; k0 < NF; k0 += 32) {
        f32x4 h0 = *reinterpret_cast<const f32x4*>(hrow + k0);
        f32x4 h1 = *reinterpret_cast<const f32x4*>(hrow + k0 + 4);
        f32x4 w1lo = *reinterpret_cast<const f32x4*>(&wa1[k0 + kofs]);
        f32x4 w1hi = *reinterpret_cast<const f32x4*>(&wa1[k0 + kofs + 4]);
        f32x4 w2lo = *reinterpret_cast<const f32x4*>(&wa2[k0 + kofs]);
        f32x4 w2hi = *reinterpret_cast<const f32x4*>(&wa2[k0 + kofs + 4]);
        short8 af;
        #pragma unroll
        for (int e = 0; e < 4; ++e) {
            s1 += h0[e] * w1lo[e] + h1[e] * w1hi[e];
            s2 += h0[e] * w2lo[e] + h1[e] * w2hi[e];
            af[e]     = (short)f2bf(h0[e]);
            af[4 + e] = (short)f2bf(h1[e]);
        }
        const int ib = (2 * (k0 + kofs)) ^ swz;
        #pragma unroll
        for (int nt = 0; nt < 8; ++nt) {
            short8 bf8 = *reinterpret_cast<short8*>(&WT[(nt * 16 + l15) * 256 + ib]);
            acc[nt] = __builtin_amdgcn_mfma_f32_16x16x32_bf16(af, bf8, acc[nt], 0, 0, 0);
        }
    }

    s1 += __shfl_xor(s1, 16); s1 += __shfl_xor(s1, 32);
    s2 += __shfl_xor(s2, 16); s2 += __shfl_xor(s2, 32);
    if (lane < 16) {
        siC[b * NN + arow] = s1;
        sjC[b * NN + arow] = s2;
    }

    const int J0 = i0 + w * 16 + ((lane >> 4) << 2);
    const int s = J0 >> 5;
    const int jq = (J0 >> 3) & 3;
    const int eh = J0 & 7;
    #pragma unroll
    for (int nt = 0; nt < 8; ++nt) {
        ushort4v pk;
        #pragma unroll
        for (int e = 0; e < 4; ++e) pk[e] = f2bf(acc[nt][e]);
        *reinterpret_cast<ushort4v*>(
            vfrag + (((size_t)(b * 64 + s) * 8 + nt) * 64 + (l15 | (jq << 4))) * 8 + eh) = pk;
    }
}

// ---------------------------------------------------------------------------
// Kernel B: biasF in A-fragment order (fp16):
// biasF[iblk][s][lane][e] = bias[iblk*16 + (lane&15)][s*32 + (lane>>4)*8 + e]
// ---------------------------------------------------------------------------
__global__ __launch_bounds__(256) void k_bias(
    const int* __restrict__ adj, const float* __restrict__ dist,
    const float* __restrict__ scaler, _Float16* __restrict__ biasF)
{
    __shared__ __align__(16) _Float16 st[8][64][8];  // 8KB
    const int t = threadIdx.x;
    const int iblk = blockIdx.x >> 3;
    const int jch = blockIdx.x & 7;
    const int i_l = t >> 4;
    const int o2 = t & 15;
    const int i = iblk * 16 + i_l;
    const int jbase = jch * 256 + o2 * 16;
    const float sc = scaler[0];

    const int* ap = adj + (size_t)i * NN + jbase;
    const float* dp = dist + (size_t)i * NN + jbase;
    int av[16]; float dv[16];
    *reinterpret_cast<int4*>(&av[0])  = *reinterpret_cast<const int4*>(ap);
    *reinterpret_cast<int4*>(&av[4])  = *reinterpret_cast<const int4*>(ap + 4);
    *reinterpret_cast<int4*>(&av[8])  = *reinterpret_cast<const int4*>(ap + 8);
    *reinterpret_cast<int4*>(&av[12]) = *reinterpret_cast<const int4*>(ap + 12);
    *reinterpret_cast<float4*>(&dv[0])  = *reinterpret_cast<const float4*>(dp);
    *reinterpret_cast<float4*>(&dv[4])  = *reinterpret_cast<const float4*>(dp + 4);
    *reinterpret_cast<float4*>(&dv[8])  = *reinterpret_cast<const float4*>(dp + 8);
    *reinterpret_cast<float4*>(&dv[12]) = *reinterpret_cast<const float4*>(dp + 12);

    #pragma unroll
    for (int u = 0; u < 2; ++u) {
        const int sl = (o2 * 2 + u) >> 2;
        const int jq = (o2 * 2 + u) & 3;
        f16x8 pk;
        #pragma unroll
        for (int e = 0; e < 8; ++e) {
            const int idx = u * 8 + e;
            float v = (av[idx] > 0) ? (-__log2f(dv[idx] + 1e-6f) * sc) : MASK_NEG_H;
            pk[e] = (_Float16)v;
        }
        *reinterpret_cast<f16x8*>(&st[sl][i_l | (jq << 4)][0]) = pk;
    }
    __syncthreads();

    const int w = t >> 6, lane = t & 63;
    #pragma unroll
    for (int sub = 0; sub < 2; ++sub) {
        const int fs = w * 2 + sub;
        *reinterpret_cast<f16x8*>(
            biasF + ((size_t)(iblk * 64 + jch * 8 + fs) * 64 + lane) * 8) =
            *reinterpret_cast<f16x8*>(&st[fs][lane][0]);
    }
}

// ---------------------------------------------------------------------------
// Kernel C: barrier-free main loop, all loads frag-contiguous.
// Swizzle: XCD x owns rg64s [4x..4x+3] x all 8 batches x both col-halves,
// so the 16 blocks sharing a 256KB bias slice are co-resident on one XCD
// (bias 1MB + V 4MB working set per XCD). Wave = 4 rowsets x 4 col-tiles x
// 8 K-steps; no main-loop LDS/barriers; half-acc LDS tree + split epilogue.
// ---------------------------------------------------------------------------
__global__ __launch_bounds__(512, 4) void k_attn(
    const unsigned short* __restrict__ vfrag, const float* __restrict__ siC,
    const float* __restrict__ sjC, const _Float16* __restrict__ biasF,
    float* __restrict__ out)
{
    __shared__ __align__(16) float red[4][2048];   // 4 x 8KB
    __shared__ float lp[8][4][16];                 // 2KB

    const int t = threadIdx.x;
    const int lane = t & 63;
    const int w = t >> 6;          // js 0..7
    const int l15 = lane & 15;
    const int hi = lane >> 4;

    // bias-sharing-aware XCD swizzle
    const int bid = blockIdx.x;
    const int xcd = bid & 7;
    const int seq = bid >> 3;      // 0..63
    const int rgl = seq >> 4;      // 0..3
    const int sub = seq & 15;
    const int b  = sub >> 1;       // batch
    const int ch = sub & 1;        // col half
    const int rg = xcd * 4 + rgl;  // 0..31 (64-row group)

    float si_r[4];
    #pragma unroll
    for (int rs = 0; rs < 4; ++rs)
        si_r[rs] = siC[b * NN + rg * 64 + rs * 16 + l15];

    const float* sjp = sjC + b * NN + w * 256 + hi * 8;
    const _Float16* bp[4];
    #pragma unroll
    for (int rs = 0; rs < 4; ++rs)
        bp[rs] = biasF + ((size_t)((rg * 4 + rs) * 64 + w * 8) * 64 + lane) * 8;
    const unsigned short* vp[4];
    #pragma unroll
    for (int ct = 0; ct < 4; ++ct)
        vp[ct] = vfrag + (((size_t)(b * 64 + w * 8) * 8 + ch * 4 + ct) * 64 + lane) * 8;

    f32x4 acc[4][4];
    #pragma unroll
    for (int rs = 0; rs < 4; ++rs)
        #pragma unroll
        for (int ct = 0; ct < 4; ++ct) acc[rs][ct] = (f32x4)(0.f);
    float ls[4] = {0.f, 0.f, 0.f, 0.f};

    #pragma unroll 2
    for (int sl = 0; sl < 8; ++sl) {
        f32x4 sj0 = *reinterpret_cast<const f32x4*>(sjp + sl * 32);
        f32x4 sj1 = *reinterpret_cast<const f32x4*>(sjp + sl * 32 + 4);
        short8 pa[4];
        #pragma unroll
        for (int rs = 0; rs < 4; ++rs) {
            f16x8 bv = *reinterpret_cast<const f16x8*>(bp[rs] + sl * 512);
            #pragma unroll
            for (int e = 0; e < 8; ++e) {
                float x = si_r[rs] + ((e < 4) ? sj0[e] : sj1[e - 4]);
                float y = fmaxf(x, 0.2f * x) + (float)bv[e];
                float p = __builtin_amdgcn_exp2f(y);
                ls[rs] += p;
                pa[rs][e] = (short)f2bf(p);
            }
        }
        #pragma unroll
        for (int ct = 0; ct < 4; ++ct) {
            const short8 bfr = *reinterpret_cast<const short8*>(vp[ct] + sl * 4096);
            #pragma unroll
            for (int rs = 0; rs < 4; ++rs)
                acc[rs][ct] = __builtin_amdgcn_mfma_f32_16x16x32_bf16(pa[rs], bfr, acc[rs][ct], 0, 0, 0);
        }
    }

    #pragma unroll
    for (int rs = 0; rs < 4; ++rs) {
        ls[rs] += __shfl_xor(ls[rs], 16);
        ls[rs] += __shfl_xor(ls[rs], 32);
    }
    if (lane < 16) {
        #pragma unroll
        for (int rs = 0; rs < 4; ++rs) lp[w][rs][l15] = ls[rs];
    }

    #define WHALF(r, hh) { _Pragma("unroll") for (int rs = 0; rs < 4; ++rs)      \
        _Pragma("unroll") for (int c2 = 0; c2 < 2; ++c2)                         \
        *reinterpret_cast<f32x4*>(&red[r][((rs * 2 + c2) * 64 + lane) * 4]) =    \
            acc[rs][(hh) * 2 + c2]; }
    #define AHALF(r, hh) { _Pragma("unroll") for (int rs = 0; rs < 4; ++rs)      \
        _Pragma("unroll") for (int c2 = 0; c2 < 2; ++c2)                         \
        acc[rs][(hh) * 2 + c2] +=                                                \
            *reinterpret_cast<const f32x4*>(&red[r][((rs * 2 + c2) * 64 + lane) * 4]); }

    if (w & 1) WHALF(w >> 1, 0)
    __syncthreads();
    if (!(w & 1)) AHALF(w >> 1, 0)
    __syncthreads();
    if (w & 1) WHALF(w >> 1, 1)
    __syncthreads();
    if (!(w & 1)) AHALF(w >> 1, 1)
    __syncthreads();
    if (w == 2) WHALF(0, 0)
    if (w == 6) WHALF(1, 0)
    __syncthreads();
    if (w == 0) AHALF(0, 0)
    if (w == 4) AHALF(1, 0)
    __syncthreads();
    if (w == 2) WHALF(0, 1)
    if (w == 6) WHALF(1, 1)
    __syncthreads();
    if (w == 0) AHALF(0, 1)
    if (w == 4) AHALF(1, 1)
    __syncthreads();
    if (w == 4) WHALF(0, 0)
    if (w == 0) WHALF(1, 1)
    __syncthreads();
    if (w == 0) AHALF(0, 0)
    if (w == 4) AHALF(1, 1)

    if (w == 0 || w == 4) {
        const int ctb = (w == 0) ? 0 : 2;
        #pragma unroll
        for (int rs = 0; rs < 4; ++rs) {
            float linv[4];
            #pragma unroll
            for (int e = 0; e < 4; ++e) {
                float tot = 0.f;
                #pragma unroll
                for (int q = 0; q < 8; ++q) tot += lp[q][rs][(hi << 2) | e];
                linv[e] = 1.0f / tot;
            }
            #pragma unroll
            for (int c2 = 0; c2 < 2; ++c2) {
                const int col = ch * 64 + (ctb + c2) * 16 + l15;
                #pragma unroll
                for (int e = 0; e < 4; ++e) {
                    const int row = rg * 64 + rs * 16 + (hi << 2) + e;
                    float v = acc[rs][ctb + c2][e] * linv[e];
                    v = (v > 0.f) ? v : expm1f(v);
                    out[(size_t)(b * NN + row) * NF + col] = v;
                }
            }
        }
    }
    #undef WHALF
    #undef AHALF
}

extern "C" void kernel_launch(void* const* d_in, const int* in_sizes, int n_in,
                              void* d_out, int out_size, void* d_ws, size_t ws_size,
                              hipStream_t stream) {
    (void)in_sizes; (void)n_in; (void)out_size; (void)ws_size;
    const float* h      = (const float*)d_in[0];
    const int*   adj    = (const int*)d_in[1];
    const float* dist   = (const float*)d_in[2];
    const float* W      = (const float*)d_in[3];
    const float* a      = (const float*)d_in[4];
    const float* scaler = (const float*)d_in[5];
    float* out = (float*)d_out;

    char* ws = (char*)d_ws;
    unsigned short* vfrag = (unsigned short*)ws;                     // 4 MiB
    float* siC      = (float*)(ws + 4 * 1024 * 1024);                // 64 KiB
    float* sjC      = (float*)(ws + 4 * 1024 * 1024 + 65536);        // 64 KiB
    _Float16* biasF = (_Float16*)(ws + 4 * 1024 * 1024 + 2 * 65536); // 8 MiB

    k_hprime<<<dim3(NB * NN / 64), dim3(256), 0, stream>>>(h, W, a, vfrag, siC, sjC);
    k_bias<<<dim3(128 * 8), dim3(256), 0, stream>>>(adj, dist, scaler, biasF);
    k_attn<<<dim3(NB * NN / 32), dim3(512), 0, stream>>>(vfrag, siC, sjC, biasF, out);
}

// Round 7
// 60.219 us; speedup vs baseline: 1.6781x; 1.6667x over previous
//
#include <hip/hip_runtime.h>
#include <hip/hip_bf16.h>

typedef __attribute__((ext_vector_type(4))) float f32x4;
typedef __attribute__((ext_vector_type(8))) short short8;
typedef __attribute__((ext_vector_type(4))) unsigned short ushort4v;
typedef _Float16 f16x8 __attribute__((ext_vector_type(8)));

#define NB 8
#define NN 2048
#define NF 128
#define LOG2E 1.4426950408889634f
#define MASK_NEG_H -60000.0f

static __device__ __forceinline__ unsigned short f2bf(float f) {
    union { __hip_bfloat16 b; unsigned short u; } cv;
    cv.b = __float2bfloat16(f);
    return cv.u;
}

// ---------------------------------------------------------------------------
// Kernel A: h_prime = h @ W via bf16 MFMA -> vfrag (B-fragment order:
// vfrag[b][s][colt][lane][e]); siC/sjC = (h @ (W@a1,2)) * log2e fp32.
// ---------------------------------------------------------------------------
__global__ __launch_bounds__(256) void k_hprime(
    const float* __restrict__ h, const float* __restrict__ W,
    const float* __restrict__ a, unsigned short* __restrict__ vfrag,
    float* __restrict__ siC, float* __restrict__ sjC)
{
    __shared__ __align__(16) unsigned char WT[32768];  // W^T bf16, swizzled [col][f]
    __shared__ float wa1[NF], wa2[NF];

    const int t = threadIdx.x;
    const int lane = t & 63;
    const int w = t >> 6;                 // 4 waves
    const int b = blockIdx.x >> 5;
    const int i0 = (blockIdx.x & 31) << 6;

    {
        const int f = t >> 1;             // 0..127
        const int c0 = (t & 1) << 6;      // 0 or 64
        float s1 = 0.f, s2 = 0.f;
        const float* wrow = W + f * NF + c0;
        const float* a1p = a + c0;
        const float* a2p = a + NF + c0;
        #pragma unroll 8
        for (int c = 0; c < 64; ++c) {
            float wv = wrow[c];
            s1 += wv * a1p[c];
            s2 += wv * a2p[c];
            int col = c0 + c;
            int dst = col * 256 + ((2 * f) ^ ((col & 15) << 4));
            *reinterpret_cast<unsigned short*>(&WT[dst]) = f2bf(wv);
        }
        s1 += __shfl_xor(s1, 1);
        s2 += __shfl_xor(s2, 1);
        if ((t & 1) == 0) { wa1[f] = s1 * LOG2E; wa2[f] = s2 * LOG2E; }
    }
    __syncthreads();

    const int l15 = lane & 15;
    const int arow = i0 + w * 16 + l15;
    const int kofs = (lane >> 4) << 3;    // 0,8,16,24
    const float* hrow = h + (size_t)(b * NN + arow) * NF + kofs;
    const int swz = l15 << 4;

    f32x4 acc[8];
    #pragma unroll
    for (int nt = 0; nt < 8; ++nt) acc[nt] = (f32x4)(0.f);
    float s1 = 0.f, s2 = 0.f;

    #pragma unroll
    for (int k0 = 0; k0 < NF; k0 += 32) {
        f32x4 h0 = *reinterpret_cast<const f32x4*>(hrow + k0);
        f32x4 h1 = *reinterpret_cast<const f32x4*>(hrow + k0 + 4);
        f32x4 w1lo = *reinterpret_cast<const f32x4*>(&wa1[k0 + kofs]);
        f32x4 w1hi = *reinterpret_cast<const f32x4*>(&wa1[k0 + kofs + 4]);
        f32x4 w2lo = *reinterpret_cast<const f32x4*>(&wa2[k0 + kofs]);
        f32x4 w2hi = *reinterpret_cast<const f32x4*>(&wa2[k0 + kofs + 4]);
        short8 af;
        #pragma unroll
        for (int e = 0; e < 4; ++e) {
            s1 += h0[e] * w1lo[e] + h1[e] * w1hi[e];
            s2 += h0[e] * w2lo[e] + h1[e] * w2hi[e];
            af[e]     = (short)f2bf(h0[e]);
            af[4 + e] = (short)f2bf(h1[e]);
        }
        const int ib = (2 * (k0 + kofs)) ^ swz;
        #pragma unroll
        for (int nt = 0; nt < 8; ++nt) {
            short8 bf8 = *reinterpret_cast<short8*>(&WT[(nt * 16 + l15) * 256 + ib]);
            acc[nt] = __builtin_amdgcn_mfma_f32_16x16x32_bf16(af, bf8, acc[nt], 0, 0, 0);
        }
    }

    s1 += __shfl_xor(s1, 16); s1 += __shfl_xor(s1, 32);
    s2 += __shfl_xor(s2, 16); s2 += __shfl_xor(s2, 32);
    if (lane < 16) {
        siC[b * NN + arow] = s1;
        sjC[b * NN + arow] = s2;
    }

    const int J0 = i0 + w * 16 + ((lane >> 4) << 2);
    const int s = J0 >> 5;
    const int jq = (J0 >> 3) & 3;
    const int eh = J0 & 7;
    #pragma unroll
    for (int nt = 0; nt < 8; ++nt) {
        ushort4v pk;
        #pragma unroll
        for (int e = 0; e < 4; ++e) pk[e] = f2bf(acc[nt][e]);
        *reinterpret_cast<ushort4v*>(
            vfrag + (((size_t)(b * 64 + s) * 8 + nt) * 64 + (l15 | (jq << 4))) * 8 + eh) = pk;
    }
}

// ---------------------------------------------------------------------------
// Kernel B: biasF in A-fragment order (fp16):
// biasF[iblk][s][lane][e] = bias[iblk*16 + (lane&15)][s*32 + (lane>>4)*8 + e]
// ---------------------------------------------------------------------------
__global__ __launch_bounds__(256) void k_bias(
    const int* __restrict__ adj, const float* __restrict__ dist,
    const float* __restrict__ scaler, _Float16* __restrict__ biasF)
{
    __shared__ __align__(16) _Float16 st[8][64][8];  // 8KB
    const int t = threadIdx.x;
    const int iblk = blockIdx.x >> 3;
    const int jch = blockIdx.x & 7;
    const int i_l = t >> 4;
    const int o2 = t & 15;
    const int i = iblk * 16 + i_l;
    const int jbase = jch * 256 + o2 * 16;
    const float sc = scaler[0];

    const int* ap = adj + (size_t)i * NN + jbase;
    const float* dp = dist + (size_t)i * NN + jbase;
    int av[16]; float dv[16];
    *reinterpret_cast<int4*>(&av[0])  = *reinterpret_cast<const int4*>(ap);
    *reinterpret_cast<int4*>(&av[4])  = *reinterpret_cast<const int4*>(ap + 4);
    *reinterpret_cast<int4*>(&av[8])  = *reinterpret_cast<const int4*>(ap + 8);
    *reinterpret_cast<int4*>(&av[12]) = *reinterpret_cast<const int4*>(ap + 12);
    *reinterpret_cast<float4*>(&dv[0])  = *reinterpret_cast<const float4*>(dp);
    *reinterpret_cast<float4*>(&dv[4])  = *reinterpret_cast<const float4*>(dp + 4);
    *reinterpret_cast<float4*>(&dv[8])  = *reinterpret_cast<const float4*>(dp + 8);
    *reinterpret_cast<float4*>(&dv[12]) = *reinterpret_cast<const float4*>(dp + 12);

    #pragma unroll
    for (int u = 0; u < 2; ++u) {
        const int sl = (o2 * 2 + u) >> 2;
        const int jq = (o2 * 2 + u) & 3;
        f16x8 pk;
        #pragma unroll
        for (int e = 0; e < 8; ++e) {
            const int idx = u * 8 + e;
            float v = (av[idx] > 0) ? (-__log2f(dv[idx] + 1e-6f) * sc) : MASK_NEG_H;
            pk[e] = (_Float16)v;
        }
        *reinterpret_cast<f16x8*>(&st[sl][i_l | (jq << 4)][0]) = pk;
    }
    __syncthreads();

    const int w = t >> 6, lane = t & 63;
    #pragma unroll
    for (int sub = 0; sub < 2; ++sub) {
        const int fs = w * 2 + sub;
        *reinterpret_cast<f16x8*>(
            biasF + ((size_t)(iblk * 64 + jch * 8 + fs) * 64 + lane) * 8) =
            *reinterpret_cast<f16x8*>(&st[fs][lane][0]);
    }
}

// ---------------------------------------------------------------------------
// Kernel C: barrier-free main loop, frag-contiguous loads, NO SPILL:
// wave state = acc[2][4] (32 VGPR) + pa[2] + bv[2]  (~90 VGPR total).
// Block = 64 rows x 64 cols (ch): 8 waves = 2 row-halves (rw) x 4 j-quarters
// (jq, 512 j each, 16 K-steps). XCD swizzle: XCD owns 4 rg64 x 8b x 2ch.
// Tail: 4-partial LDS tree (32KB) + 2-wave epilogue.
// ---------------------------------------------------------------------------
__global__ __launch_bounds__(512, 4) void k_attn(
    const unsigned short* __restrict__ vfrag, const float* __restrict__ siC,
    const float* __restrict__ sjC, const _Float16* __restrict__ biasF,
    float* __restrict__ out)
{
    __shared__ __align__(16) float red[4][2048];   // 4 x 8KB
    __shared__ float lp[4][2][2][16];              // 1KB

    const int t = threadIdx.x;
    const int lane = t & 63;
    const int w = t >> 6;          // 0..7
    const int rw = w & 1;          // row half (32 rows)
    const int jq = w >> 1;         // j quarter (512 j)
    const int l15 = lane & 15;
    const int hi = lane >> 4;

    const int bid = blockIdx.x;
    const int xcd = bid & 7;
    const int seq = bid >> 3;      // 0..63
    const int rgl = seq >> 4;      // 0..3
    const int sub = seq & 15;
    const int b  = sub >> 1;
    const int ch = sub & 1;
    const int rg = xcd * 4 + rgl;  // 64-row group 0..31

    const int rowbase = rg * 64 + rw * 32;
    const float si0 = siC[b * NN + rowbase + l15];
    const float si1 = siC[b * NN + rowbase + 16 + l15];

    const float* sjp = sjC + b * NN + jq * 512 + hi * 8;
    const int iblk0 = rg * 4 + rw * 2;
    const _Float16* bp0 = biasF + ((size_t)(iblk0 * 64 + jq * 16) * 64 + lane) * 8;
    const _Float16* bp1 = bp0 + 32768;   // next iblk (64*64*8)
    const unsigned short* vpp = vfrag +
        (((size_t)(b * 64 + jq * 16) * 8) + ch * 4) * 512;

    f32x4 acc[2][4];
    #pragma unroll
    for (int rs = 0; rs < 2; ++rs)
        #pragma unroll
        for (int ct = 0; ct < 4; ++ct) acc[rs][ct] = (f32x4)(0.f);
    float ls0 = 0.f, ls1 = 0.f;

    #pragma unroll 4
    for (int sl = 0; sl < 16; ++sl) {
        f32x4 sj0 = *reinterpret_cast<const f32x4*>(sjp + sl * 32);
        f32x4 sj1 = *reinterpret_cast<const f32x4*>(sjp + sl * 32 + 4);
        f16x8 bv0 = *reinterpret_cast<const f16x8*>(bp0 + sl * 512);
        f16x8 bv1 = *reinterpret_cast<const f16x8*>(bp1 + sl * 512);
        short8 pa0, pa1;
        #pragma unroll
        for (int e = 0; e < 8; ++e) {
            const float sjv = (e < 4) ? sj0[e] : sj1[e - 4];
            float x0 = si0 + sjv;
            x0 = fmaxf(x0, 0.2f * x0) + (float)bv0[e];
            float p0 = __builtin_amdgcn_exp2f(x0);
            ls0 += p0;
            pa0[e] = (short)f2bf(p0);
            float x1 = si1 + sjv;
            x1 = fmaxf(x1, 0.2f * x1) + (float)bv1[e];
            float p1 = __builtin_amdgcn_exp2f(x1);
            ls1 += p1;
            pa1[e] = (short)f2bf(p1);
        }
        const unsigned short* vs = vpp + sl * 4096;
        #pragma unroll
        for (int ct = 0; ct < 4; ++ct) {
            const short8 bfr = *reinterpret_cast<const short8*>(vs + ct * 512 + lane * 8);
            acc[0][ct] = __builtin_amdgcn_mfma_f32_16x16x32_bf16(pa0, bfr, acc[0][ct], 0, 0, 0);
            acc[1][ct] = __builtin_amdgcn_mfma_f32_16x16x32_bf16(pa1, bfr, acc[1][ct], 0, 0, 0);
        }
    }

    ls0 += __shfl_xor(ls0, 16); ls0 += __shfl_xor(ls0, 32);
    ls1 += __shfl_xor(ls1, 16); ls1 += __shfl_xor(ls1, 32);
    if (lane < 16) { lp[jq][rw][0][l15] = ls0; lp[jq][rw][1][l15] = ls1; }

    #define WACC(buf) { _Pragma("unroll") for (int rs = 0; rs < 2; ++rs)      \
        _Pragma("unroll") for (int ct = 0; ct < 4; ++ct)                      \
        *reinterpret_cast<f32x4*>(&red[buf][((rs * 4 + ct) * 64 + lane) * 4]) \
            = acc[rs][ct]; }
    #define AACC(buf) { _Pragma("unroll") for (int rs = 0; rs < 2; ++rs)      \
        _Pragma("unroll") for (int ct = 0; ct < 4; ++ct)                      \
        acc[rs][ct] += *reinterpret_cast<const f32x4*>(                       \
            &red[buf][((rs * 4 + ct) * 64 + lane) * 4]); }

    if (jq == 1 || jq == 3) WACC(rw * 2 + (jq >> 1))
    __syncthreads();
    if (jq == 0 || jq == 2) AACC(rw * 2 + (jq >> 1))
    __syncthreads();
    if (jq == 2) WACC(rw * 2)
    __syncthreads();
    if (jq == 0) AACC(rw * 2)

    if (jq == 0) {
        float linv[2][4];
        #pragma unroll
        for (int rs = 0; rs < 2; ++rs)
            #pragma unroll
            for (int e = 0; e < 4; ++e) {
                const int rr = (hi << 2) + e;
                linv[rs][e] = 1.0f / (lp[0][rw][rs][rr] + lp[1][rw][rs][rr]
                                    + lp[2][rw][rs][rr] + lp[3][rw][rs][rr]);
            }
        #pragma unroll
        for (int rs = 0; rs < 2; ++rs)
            #pragma unroll
            for (int ct = 0; ct < 4; ++ct) {
                const int col = ch * 64 + ct * 16 + l15;
                #pragma unroll
                for (int e = 0; e < 4; ++e) {
                    const int row = rowbase + rs * 16 + (hi << 2) + e;
                    float v = acc[rs][ct][e] * linv[rs][e];
                    v = (v > 0.f) ? v : expm1f(v);
                    out[(size_t)(b * NN + row) * NF + col] = v;
                }
            }
    }
    #undef WACC
    #undef AACC
}

extern "C" void kernel_launch(void* const* d_in, const int* in_sizes, int n_in,
                              void* d_out, int out_size, void* d_ws, size_t ws_size,
                              hipStream_t stream) {
    (void)in_sizes; (void)n_in; (void)out_size; (void)ws_size;
    const float* h      = (const float*)d_in[0];
    const int*   adj    = (const int*)d_in[1];
    const float* dist   = (const float*)d_in[2];
    const float* W      = (const float*)d_in[3];
    const float* a      = (const float*)d_in[4];
    const float* scaler = (const float*)d_in[5];
    float* out = (float*)d_out;

    char* ws = (char*)d_ws;
    unsigned short* vfrag = (unsigned short*)ws;                     // 4 MiB
    float* siC      = (float*)(ws + 4 * 1024 * 1024);                // 64 KiB
    float* sjC      = (float*)(ws + 4 * 1024 * 1024 + 65536);        // 64 KiB
    _Float16* biasF = (_Float16*)(ws + 4 * 1024 * 1024 + 2 * 65536); // 8 MiB

    k_hprime<<<dim3(NB * NN / 64), dim3(256), 0, stream>>>(h, W, a, vfrag, siC, sjC);
    k_bias<<<dim3(128 * 8), dim3(256), 0, stream>>>(adj, dist, scaler, biasF);
    k_attn<<<dim3(NB * NN / 32), dim3(512), 0, stream>>>(vfrag, siC, sjC, biasF, out);
}

// Round 8
// 50.467 us; speedup vs baseline: 2.0024x; 1.1932x over previous
//
#include <hip/hip_runtime.h>
#include <hip/hip_bf16.h>

typedef __attribute__((ext_vector_type(4))) float f32x4;
typedef __attribute__((ext_vector_type(8))) short short8;
typedef __attribute__((ext_vector_type(4))) unsigned short ushort4v;
typedef _Float16 f16x8 __attribute__((ext_vector_type(8)));

#define NB 8
#define NN 2048
#define NF 128
#define LOG2E 1.4426950408889634f
#define MASK_NEG_H -60000.0f

static __device__ __forceinline__ unsigned short f2bf(float f) {
    union { __hip_bfloat16 b; unsigned short u; } cv;
    cv.b = __float2bfloat16(f);
    return cv.u;
}

// ---------------------------------------------------------------------------
// Kernel PRE (fused): blocks 0..255 = hprime (h@W -> vfrag B-frags, si/sj);
// blocks 256..1279 = bias -> biasF A-frags (fp16). Single launch overlaps
// hprime's compute with bias's HBM streaming.
// ---------------------------------------------------------------------------
__global__ __launch_bounds__(256) void k_pre(
    const float* __restrict__ h, const int* __restrict__ adj,
    const float* __restrict__ dist, const float* __restrict__ W,
    const float* __restrict__ a, const float* __restrict__ scaler,
    unsigned short* __restrict__ vfrag, float* __restrict__ siC,
    float* __restrict__ sjC, _Float16* __restrict__ biasF)
{
    __shared__ __align__(16) unsigned char smem[34816];
    const int bid = blockIdx.x;
    const int t = threadIdx.x;

    if (bid < 256) {
        // ================= hprime =================
        unsigned char* WT = smem;                  // 32KB swizzled W^T bf16
        float* wa1 = (float*)(smem + 32768);
        float* wa2 = wa1 + NF;

        const int lane = t & 63;
        const int w = t >> 6;
        const int b = bid >> 5;
        const int i0 = (bid & 31) << 6;

        {
            const int f = t >> 1;
            const int c0 = (t & 1) << 6;
            float s1 = 0.f, s2 = 0.f;
            const float* wrow = W + f * NF + c0;
            const float* a1p = a + c0;
            const float* a2p = a + NF + c0;
            #pragma unroll 8
            for (int c = 0; c < 64; ++c) {
                float wv = wrow[c];
                s1 += wv * a1p[c];
                s2 += wv * a2p[c];
                int col = c0 + c;
                int dst = col * 256 + ((2 * f) ^ ((col & 15) << 4));
                *reinterpret_cast<unsigned short*>(&WT[dst]) = f2bf(wv);
            }
            s1 += __shfl_xor(s1, 1);
            s2 += __shfl_xor(s2, 1);
            if ((t & 1) == 0) { wa1[f] = s1 * LOG2E; wa2[f] = s2 * LOG2E; }
        }
        __syncthreads();

        const int l15 = lane & 15;
        const int arow = i0 + w * 16 + l15;
        const int kofs = (lane >> 4) << 3;
        const float* hrow = h + (size_t)(b * NN + arow) * NF + kofs;
        const int swz = l15 << 4;

        f32x4 acc[8];
        #pragma unroll
        for (int nt = 0; nt < 8; ++nt) acc[nt] = (f32x4)(0.f);
        float s1 = 0.f, s2 = 0.f;

        #pragma unroll
        for (int k0 = 0; k0 < NF; k0 += 32) {
            f32x4 h0 = *reinterpret_cast<const f32x4*>(hrow + k0);
            f32x4 h1 = *reinterpret_cast<const f32x4*>(hrow + k0 + 4);
            f32x4 w1lo = *reinterpret_cast<const f32x4*>(&wa1[k0 + kofs]);
            f32x4 w1hi = *reinterpret_cast<const f32x4*>(&wa1[k0 + kofs + 4]);
            f32x4 w2lo = *reinterpret_cast<const f32x4*>(&wa2[k0 + kofs]);
            f32x4 w2hi = *reinterpret_cast<const f32x4*>(&wa2[k0 + kofs + 4]);
            short8 af;
            #pragma unroll
            for (int e = 0; e < 4; ++e) {
                s1 += h0[e] * w1lo[e] + h1[e] * w1hi[e];
                s2 += h0[e] * w2lo[e] + h1[e] * w2hi[e];
                af[e]     = (short)f2bf(h0[e]);
                af[4 + e] = (short)f2bf(h1[e]);
            }
            const int ib = (2 * (k0 + kofs)) ^ swz;
            #pragma unroll
            for (int nt = 0; nt < 8; ++nt) {
                short8 bf8 = *reinterpret_cast<short8*>(&WT[(nt * 16 + l15) * 256 + ib]);
                acc[nt] = __builtin_amdgcn_mfma_f32_16x16x32_bf16(af, bf8, acc[nt], 0, 0, 0);
            }
        }

        s1 += __shfl_xor(s1, 16); s1 += __shfl_xor(s1, 32);
        s2 += __shfl_xor(s2, 16); s2 += __shfl_xor(s2, 32);
        if (lane < 16) {
            siC[b * NN + arow] = s1;
            sjC[b * NN + arow] = s2;
        }

        const int J0 = i0 + w * 16 + ((lane >> 4) << 2);
        const int s = J0 >> 5;
        const int jq = (J0 >> 3) & 3;
        const int eh = J0 & 7;
        #pragma unroll
        for (int nt = 0; nt < 8; ++nt) {
            ushort4v pk;
            #pragma unroll
            for (int e = 0; e < 4; ++e) pk[e] = f2bf(acc[nt][e]);
            *reinterpret_cast<ushort4v*>(
                vfrag + (((size_t)(b * 64 + s) * 8 + nt) * 64 + (l15 | (jq << 4))) * 8 + eh) = pk;
        }
    } else {
        // ================= bias =================
        _Float16 (*st)[64][8] = (_Float16 (*)[64][8])smem;   // 8KB
        const int bid2 = bid - 256;
        const int iblk = bid2 >> 3;
        const int jch = bid2 & 7;
        const int i_l = t >> 4;
        const int o2 = t & 15;
        const int i = iblk * 16 + i_l;
        const int jbase = jch * 256 + o2 * 16;
        const float sc = scaler[0];

        const int* ap = adj + (size_t)i * NN + jbase;
        const float* dp = dist + (size_t)i * NN + jbase;
        int av[16]; float dv[16];
        *reinterpret_cast<int4*>(&av[0])  = *reinterpret_cast<const int4*>(ap);
        *reinterpret_cast<int4*>(&av[4])  = *reinterpret_cast<const int4*>(ap + 4);
        *reinterpret_cast<int4*>(&av[8])  = *reinterpret_cast<const int4*>(ap + 8);
        *reinterpret_cast<int4*>(&av[12]) = *reinterpret_cast<const int4*>(ap + 12);
        *reinterpret_cast<float4*>(&dv[0])  = *reinterpret_cast<const float4*>(dp);
        *reinterpret_cast<float4*>(&dv[4])  = *reinterpret_cast<const float4*>(dp + 4);
        *reinterpret_cast<float4*>(&dv[8])  = *reinterpret_cast<const float4*>(dp + 8);
        *reinterpret_cast<float4*>(&dv[12]) = *reinterpret_cast<const float4*>(dp + 12);

        #pragma unroll
        for (int u = 0; u < 2; ++u) {
            const int sl = (o2 * 2 + u) >> 2;
            const int jq = (o2 * 2 + u) & 3;
            f16x8 pk;
            #pragma unroll
            for (int e = 0; e < 8; ++e) {
                const int idx = u * 8 + e;
                float v = (av[idx] > 0) ? (-__log2f(dv[idx] + 1e-6f) * sc) : MASK_NEG_H;
                pk[e] = (_Float16)v;
            }
            *reinterpret_cast<f16x8*>(&st[sl][i_l | (jq << 4)][0]) = pk;
        }
        __syncthreads();

        const int w = t >> 6, lane = t & 63;
        #pragma unroll
        for (int sub = 0; sub < 2; ++sub) {
            const int fs = w * 2 + sub;
            *reinterpret_cast<f16x8*>(
                biasF + ((size_t)(iblk * 64 + jch * 8 + fs) * 64 + lane) * 8) =
                *reinterpret_cast<f16x8*>(&st[fs][lane][0]);
        }
    }
}

// ---------------------------------------------------------------------------
// Kernel C: barrier-free main loop, 32-row blocks, grid 1024 = 4 blocks/CU,
// 8 waves/SIMD (VGPR<=64 via launch_bounds(512,8)). 8 waves = 2 rw (16-row
// sets) x 4 jq (512-j strips, 16 K-steps). acc[4] = 16 VGPR. XCD swizzle:
// XCD owns 16 rg32 x 4 batches x 2 ch -> bias 2MB + V 2MB = L2-resident.
// Tail: 3-barrier tree over 4 jq partials (16KB LDS) + 2-wave epilogue.
// ---------------------------------------------------------------------------
__global__ __launch_bounds__(512, 8) void k_attn(
    const unsigned short* __restrict__ vfrag, const float* __restrict__ siC,
    const float* __restrict__ sjC, const _Float16* __restrict__ biasF,
    float* __restrict__ out)
{
    __shared__ __align__(16) float red[4][1024];   // 4 x 4KB
    __shared__ float lp[4][2][16];                 // 512B

    const int t = threadIdx.x;
    const int lane = t & 63;
    const int w = t >> 6;          // 0..7
    const int rw = w & 1;          // 16-row set
    const int jq = w >> 1;         // 512-j strip
    const int l15 = lane & 15;
    const int hi = lane >> 4;

    const int bid = blockIdx.x;
    const int xcd = bid & 7;
    const int seq = bid >> 3;      // 0..127
    const int rg = (xcd & 3) * 16 + (seq >> 3);     // 32-row group 0..63
    const int b  = (xcd >> 2) * 4 + ((seq >> 1) & 3);
    const int ch = seq & 1;

    const int rowbase = rg * 32 + rw * 16;
    const float si0 = siC[b * NN + rowbase + l15];

    const float* sjp = sjC + b * NN + jq * 512 + hi * 8;
    const int iblk = rg * 2 + rw;
    const _Float16* bp = biasF + ((size_t)(iblk * 64 + jq * 16) * 64 + lane) * 8;
    const unsigned short* vpp = vfrag +
        (((size_t)(b * 64 + jq * 16) * 8) + ch * 4) * 512 + lane * 8;

    f32x4 acc[4];
    #pragma unroll
    for (int ct = 0; ct < 4; ++ct) acc[ct] = (f32x4)(0.f);
    float ls0 = 0.f;

    #pragma unroll 4
    for (int sl = 0; sl < 16; ++sl) {
        f32x4 sj0 = *reinterpret_cast<const f32x4*>(sjp + sl * 32);
        f32x4 sj1 = *reinterpret_cast<const f32x4*>(sjp + sl * 32 + 4);
        f16x8 bv = *reinterpret_cast<const f16x8*>(bp + sl * 512);
        short8 pa;
        #pragma unroll
        for (int e = 0; e < 8; ++e) {
            const float sjv = (e < 4) ? sj0[e] : sj1[e - 4];
            float x = si0 + sjv;
            x = fmaxf(x, 0.2f * x) + (float)bv[e];
            float p = __builtin_amdgcn_exp2f(x);
            ls0 += p;
            pa[e] = (short)f2bf(p);
        }
        const unsigned short* vs = vpp + sl * 4096;
        #pragma unroll
        for (int ct = 0; ct < 4; ++ct) {
            const short8 bfr = *reinterpret_cast<const short8*>(vs + ct * 512);
            acc[ct] = __builtin_amdgcn_mfma_f32_16x16x32_bf16(pa, bfr, acc[ct], 0, 0, 0);
        }
    }

    ls0 += __shfl_xor(ls0, 16);
    ls0 += __shfl_xor(ls0, 32);
    if (lane < 16) lp[jq][rw][l15] = ls0;

    #define WACC(buf) { _Pragma("unroll") for (int ct = 0; ct < 4; ++ct)       \
        *reinterpret_cast<f32x4*>(&red[buf][(ct * 64 + lane) * 4]) = acc[ct]; }
    #define AACC(buf) { _Pragma("unroll") for (int ct = 0; ct < 4; ++ct)       \
        acc[ct] += *reinterpret_cast<const f32x4*>(                            \
            &red[buf][(ct * 64 + lane) * 4]); }

    if (jq == 1) WACC(rw * 2)
    if (jq == 3) WACC(rw * 2 + 1)
    __syncthreads();
    if (jq == 0) AACC(rw * 2)
    if (jq == 2) AACC(rw * 2 + 1)
    __syncthreads();
    if (jq == 2) WACC(rw * 2)
    __syncthreads();
    if (jq == 0) {
        AACC(rw * 2)
        float linv[4];
        #pragma unroll
        for (int e = 0; e < 4; ++e) {
            const int rr = (hi << 2) + e;
            linv[e] = 1.0f / (lp[0][rw][rr] + lp[1][rw][rr]
                            + lp[2][rw][rr] + lp[3][rw][rr]);
        }
        #pragma unroll
        for (int ct = 0; ct < 4; ++ct) {
            const int col = ch * 64 + ct * 16 + l15;
            #pragma unroll
            for (int e = 0; e < 4; ++e) {
                const int row = rowbase + (hi << 2) + e;
                float v = acc[ct][e] * linv[e];
                v = (v > 0.f) ? v : expm1f(v);
                out[(size_t)(b * NN + row) * NF + col] = v;
            }
        }
    }
    #undef WACC
    #undef AACC
}

extern "C" void kernel_launch(void* const* d_in, const int* in_sizes, int n_in,
                              void* d_out, int out_size, void* d_ws, size_t ws_size,
                              hipStream_t stream) {
    (void)in_sizes; (void)n_in; (void)out_size; (void)ws_size;
    const float* h      = (const float*)d_in[0];
    const int*   adj    = (const int*)d_in[1];
    const float* dist   = (const float*)d_in[2];
    const float* W      = (const float*)d_in[3];
    const float* a      = (const float*)d_in[4];
    const float* scaler = (const float*)d_in[5];
    float* out = (float*)d_out;

    char* ws = (char*)d_ws;
    unsigned short* vfrag = (unsigned short*)ws;                     // 4 MiB
    float* siC      = (float*)(ws + 4 * 1024 * 1024);                // 64 KiB
    float* sjC      = (float*)(ws + 4 * 1024 * 1024 + 65536);        // 64 KiB
    _Float16* biasF = (_Float16*)(ws + 4 * 1024 * 1024 + 2 * 65536); // 8 MiB

    k_pre<<<dim3(1280), dim3(256), 0, stream>>>(h, adj, dist, W, a, scaler,
                                                vfrag, siC, sjC, biasF);
    k_attn<<<dim3(NB * NN / 16), dim3(512), 0, stream>>>(vfrag, siC, sjC, biasF, out);
}